// Round 12
// baseline (521.845 us; speedup 1.0000x reference)
//
#include <hip/hip_runtime.h>
#include <stdint.h>

typedef __attribute__((ext_vector_type(4))) float f32x4;
typedef __attribute__((ext_vector_type(8))) short s16x8;

#define CC   192
#define NN   16384
#define EE   4
#define HIDD 384

// LDS map (static, 74752 B) -> 2 blocks/CU:
//  [0,     24576)  X tile [64 tok][192 ch] bf16, XOR-swizzled — resident whole kernel
//  [24576, 49152)  hid buf0 (router partials [24576,28672) pre-loop only)
//  [49152, 73728)  hid buf1
//  [73728, 74752)  gates [64 tok][4 e] f32
//  epilogue: outl [192 c][65 tok] f32 overlays X + h0
// Round 12: (1) kmoe — per-phase weight loads forced into ONE inline-asm block
// (18x global_load_dwordx4 + vmcnt(0)); R9-R11 proved the scheduler sinks any
// C-level burst back to per-kk loads (VGPR stuck ~108), serializing ~6 L2/L3
// latency exposures per phase. An asm block cannot be split. (2) kab — same
// kernel minus ALL weight loads (mfma(xk,xk)): measures the no-load floor.
// FETCH excess (115-120 vs ~101 MB ideal) suggests weights are evicted from L2
// by the x/out stream and re-fetched ~10x -> per-kk waits of 400-900 cyc.
#define OFF_H0   24576u
#define OFF_H1   49152u
#define OFF_PART 24576
#define OFF_GATE 73728
#define LDS_SZ   74752

__device__ __forceinline__ uint16_t bfbits(float f){
  uint32_t u = __builtin_bit_cast(uint32_t, f);
  u += 0x7FFFu + ((u >> 16) & 1u);
  return (uint16_t)(u >> 16);
}
__device__ __forceinline__ uint32_t pkbf(float lo, float hi){
  uint32_t ul = __builtin_bit_cast(uint32_t, lo);
  uint32_t uh = __builtin_bit_cast(uint32_t, hi);
  ul += 0x7FFFu + ((ul >> 16) & 1u);
  uh += 0x7FFFu + ((uh >> 16) & 1u);
  return (ul >> 16) | (uh & 0xFFFF0000u);
}
// tanh-form GELU, |err| <= ~3e-3 (threshold 0.109; measured absmax 0.031)
__device__ __forceinline__ float gelu_f(float v){
  float x2 = v * v;
  float z = v * __builtin_fmaf(x2, -0.1029432f, -2.3022082f);
  float e = __builtin_amdgcn_exp2f(z);
  return v * __builtin_amdgcn_rcpf(1.0f + e);
}
__device__ __forceinline__ f32x4 mfma16(s16x8 a, s16x8 b, f32x4 c){
  return __builtin_amdgcn_mfma_f32_16x16x32_bf16(a, b, c, 0, 0, 0);
}

// 18 weight fragments in ONE un-splittable asm block: all loads in flight, one
// wait. w[m*6+kk]. Bases: a_m = row block m*16; offsets kk*64B (<=320, imm ok).
__device__ __forceinline__ void load18(const uint16_t* a0, const uint16_t* a1,
                                       const uint16_t* a2, s16x8 (&w)[18]){
  asm volatile(
    "global_load_dwordx4 %0,  %[A0], off\n\t"
    "global_load_dwordx4 %1,  %[A0], off offset:64\n\t"
    "global_load_dwordx4 %2,  %[A0], off offset:128\n\t"
    "global_load_dwordx4 %3,  %[A0], off offset:192\n\t"
    "global_load_dwordx4 %4,  %[A0], off offset:256\n\t"
    "global_load_dwordx4 %5,  %[A0], off offset:320\n\t"
    "global_load_dwordx4 %6,  %[A1], off\n\t"
    "global_load_dwordx4 %7,  %[A1], off offset:64\n\t"
    "global_load_dwordx4 %8,  %[A1], off offset:128\n\t"
    "global_load_dwordx4 %9,  %[A1], off offset:192\n\t"
    "global_load_dwordx4 %10, %[A1], off offset:256\n\t"
    "global_load_dwordx4 %11, %[A1], off offset:320\n\t"
    "global_load_dwordx4 %12, %[A2], off\n\t"
    "global_load_dwordx4 %13, %[A2], off offset:64\n\t"
    "global_load_dwordx4 %14, %[A2], off offset:128\n\t"
    "global_load_dwordx4 %15, %[A2], off offset:192\n\t"
    "global_load_dwordx4 %16, %[A2], off offset:256\n\t"
    "global_load_dwordx4 %17, %[A2], off offset:320\n\t"
    "s_waitcnt vmcnt(0)"
    : "=&v"(w[0]),  "=&v"(w[1]),  "=&v"(w[2]),  "=&v"(w[3]),  "=&v"(w[4]),  "=&v"(w[5]),
      "=&v"(w[6]),  "=&v"(w[7]),  "=&v"(w[8]),  "=&v"(w[9]),  "=&v"(w[10]), "=&v"(w[11]),
      "=&v"(w[12]), "=&v"(w[13]), "=&v"(w[14]), "=&v"(w[15]), "=&v"(w[16]), "=&v"(w[17])
    : [A0]"v"(a0), [A1]"v"(a1), [A2]"v"(a2));
}

// GEMM1 phase: asm burst of 18 w1 frags, then 6 kk of {4 LDS X-reads, 12 MFMA}
__device__ __forceinline__ void g1_phase(const uint16_t* __restrict__ w1p,
                                         const unsigned char* S, const uint32_t rowb[4],
                                         uint32_t xsw, int lg, f32x4 (&acc)[3][4]){
  s16x8 w[18];
  load18(w1p, w1p + 16 * CC, w1p + 32 * CC, w);
  __builtin_amdgcn_s_setprio(1);
  #pragma unroll
  for (int kk = 0; kk < 6; ++kk){
    s16x8 xk[4];
    #pragma unroll
    for (int np = 0; np < 4; ++np)
      xk[np] = *(const s16x8*)(S + rowb[np] + (((uint32_t)(64 * kk + 16 * lg)) ^ xsw));
    #pragma unroll
    for (int np = 0; np < 4; ++np)
      #pragma unroll
      for (int m = 0; m < 3; ++m)
        acc[m][np] = mfma16(w[m * 6 + kk], xk[np], acc[m][np]);
  }
  __builtin_amdgcn_s_setprio(0);
}

// GEMM2 phase: asm burst of 18 w2 frags, then 6 kk of {4 LDS hid-reads, 12 MFMA}
__device__ __forceinline__ void g2_phase(const uint16_t* __restrict__ w2p,
                                         const unsigned char* S, uint32_t hb,
                                         const uint32_t rowb[4],
                                         uint32_t xsw, int lg, f32x4 (&acc)[3][4]){
  s16x8 w[18];
  load18(w2p, w2p + 16 * HIDD, w2p + 32 * HIDD, w);
  __builtin_amdgcn_s_setprio(1);
  #pragma unroll
  for (int kk = 0; kk < 6; ++kk){
    s16x8 hf[4];
    #pragma unroll
    for (int np = 0; np < 4; ++np)
      hf[np] = *(const s16x8*)(S + hb + rowb[np]
                               + (((uint32_t)(64 * kk + 16 * lg)) ^ xsw));
    #pragma unroll
    for (int np = 0; np < 4; ++np)
      #pragma unroll
      for (int m = 0; m < 3; ++m)
        acc[m][np] = mfma16(w[m * 6 + kk], hf[np], acc[m][np]);
  }
  __builtin_amdgcn_s_setprio(0);
}

// ---- ablation variants: NO weight loads (mfma(frag,frag)) — measures the floor
__device__ __forceinline__ void g1_phase_nl(const unsigned char* S, const uint32_t rowb[4],
                                            uint32_t xsw, int lg, f32x4 (&acc)[3][4]){
  __builtin_amdgcn_s_setprio(1);
  #pragma unroll
  for (int kk = 0; kk < 6; ++kk){
    s16x8 xk[4];
    #pragma unroll
    for (int np = 0; np < 4; ++np)
      xk[np] = *(const s16x8*)(S + rowb[np] + (((uint32_t)(64 * kk + 16 * lg)) ^ xsw));
    #pragma unroll
    for (int np = 0; np < 4; ++np)
      #pragma unroll
      for (int m = 0; m < 3; ++m)
        acc[m][np] = mfma16(xk[np], xk[np], acc[m][np]);
  }
  __builtin_amdgcn_s_setprio(0);
}
__device__ __forceinline__ void g2_phase_nl(const unsigned char* S, uint32_t hb,
                                            const uint32_t rowb[4],
                                            uint32_t xsw, int lg, f32x4 (&acc)[3][4]){
  __builtin_amdgcn_s_setprio(1);
  #pragma unroll
  for (int kk = 0; kk < 6; ++kk){
    s16x8 hf[4];
    #pragma unroll
    for (int np = 0; np < 4; ++np)
      hf[np] = *(const s16x8*)(S + hb + rowb[np]
                               + (((uint32_t)(64 * kk + 16 * lg)) ^ xsw));
    #pragma unroll
    for (int np = 0; np < 4; ++np)
      #pragma unroll
      for (int m = 0; m < 3; ++m)
        acc[m][np] = mfma16(hf[np], hf[np], acc[m][np]);
  }
  __builtin_amdgcn_s_setprio(0);
}

// GELU*gate on a hacc tile -> hid LDS buffer hb (b64 writes)
__device__ __forceinline__ void gelu_store(unsigned char* S, uint32_t hb,
                                           const uint32_t rowb[4],
                                           uint32_t xsw, int wv, int lg,
                                           const float gt[4], const f32x4 (&acc)[3][4]){
  #pragma unroll
  for (int np = 0; np < 4; ++np){
    const uint32_t tb = hb + rowb[np];
    const float g = gt[np];
    #pragma unroll
    for (int m = 0; m < 3; ++m){
      const float v0 = gelu_f(acc[m][np][0]) * g;
      const float v1 = gelu_f(acc[m][np][1]) * g;
      const float v2 = gelu_f(acc[m][np][2]) * g;
      const float v3 = gelu_f(acc[m][np][3]) * g;
      uint2 p; p.x = pkbf(v0, v1); p.y = pkbf(v2, v3);
      *(uint2*)(S + tb + (((uint32_t)(96 * wv + 32 * m + 8 * lg)) ^ xsw)) = p;
    }
  }
}

extern "C" __global__ void kconv(const float* __restrict__ w1, const float* __restrict__ w2,
                                 uint16_t* __restrict__ w1b, uint16_t* __restrict__ w2b){
  int i = blockIdx.x * 256 + threadIdx.x;
  w1b[i] = bfbits(w1[i]);
  w2b[i] = bfbits(w2[i]);
}

// Shared body: PHASES selects real (1) vs no-load ablation (0) GEMM phases.
template <int LOADS>
__device__ __forceinline__ void moe_body(
    const float* __restrict__ x, const float* __restrict__ rw,
    const float* __restrict__ rb, const uint16_t* __restrict__ w1b,
    const float* __restrict__ b1, const uint16_t* __restrict__ w2b,
    const float* __restrict__ b2, const float* __restrict__ scp,
    float* __restrict__ out, unsigned char* S)
{
  const int tid  = threadIdx.x;
  const int lane = tid & 63;
  const int wv   = tid >> 6;
  const int lq   = lane & 15;
  const int lg   = lane >> 4;
  const int tile = blockIdx.x;
  const int b    = tile >> 8;
  const int n0   = (tile & 255) << 6;
  const float* xb = x + (size_t)b * CC * NN;

  // ---- Phase 1: stage X tile (bf16, swizzled) + fp32 router partials
  {
    const int t = lane;
    const uint32_t rowbp = (uint32_t)t * 384u;
    const uint32_t sw    = ((uint32_t)(t & 7)) << 4;
    float a0 = 0.f, a1 = 0.f, a2 = 0.f, a3 = 0.f;
    #pragma unroll 8
    for (int j = 0; j < 48; j += 2){
      const int c = wv * 48 + j;
      const float v0 = xb[(size_t)c * NN + n0 + t];
      const float v1 = xb[(size_t)(c + 1) * NN + n0 + t];
      a0 = __builtin_fmaf(v1, rw[c + 1],          __builtin_fmaf(v0, rw[c],          a0));
      a1 = __builtin_fmaf(v1, rw[CC + c + 1],     __builtin_fmaf(v0, rw[CC + c],     a1));
      a2 = __builtin_fmaf(v1, rw[2 * CC + c + 1], __builtin_fmaf(v0, rw[2 * CC + c], a2));
      a3 = __builtin_fmaf(v1, rw[3 * CC + c + 1], __builtin_fmaf(v0, rw[3 * CC + c], a3));
      *(uint32_t*)(S + rowbp + (((uint32_t)(2 * c)) ^ sw)) = pkbf(v0, v1);
    }
    float* pl = (float*)(S + OFF_PART);
    pl[(wv * 4 + 0) * 64 + t] = a0;
    pl[(wv * 4 + 1) * 64 + t] = a1;
    pl[(wv * 4 + 2) * 64 + t] = a2;
    pl[(wv * 4 + 3) * 64 + t] = a3;
  }
  __syncthreads();

  // ---- Phase 2 (tid<64): router finalize -> gates
  if (tid < 64){
    const int t = tid;
    const float* pl = (const float*)(S + OFF_PART);
    float l0 = rb[0], l1 = rb[1], l2 = rb[2], l3 = rb[3];
    #pragma unroll
    for (int cg = 0; cg < 4; ++cg){
      l0 += pl[(cg * 4 + 0) * 64 + t];
      l1 += pl[(cg * 4 + 1) * 64 + t];
      l2 += pl[(cg * 4 + 2) * 64 + t];
      l3 += pl[(cg * 4 + 3) * 64 + t];
    }
    int i1 = 0; float v1 = l0;
    if (l1 > v1){ v1 = l1; i1 = 1; }
    if (l2 > v1){ v1 = l2; i1 = 2; }
    if (l3 > v1){ v1 = l3; i1 = 3; }
    float v2 = -3.0e38f; int i2 = 0;
    if (i1 != 0){ v2 = l0; i2 = 0; }
    if (i1 != 1 && l1 > v2){ v2 = l1; i2 = 1; }
    if (i1 != 2 && l2 > v2){ v2 = l2; i2 = 2; }
    if (i1 != 3 && l3 > v2){ v2 = l3; i2 = 3; }
    const float ex = __expf(v2 - v1);
    const float ga = 1.0f / (1.0f + ex);
    const float gb = ex * ga;
    float* glw = (float*)(S + OFF_GATE);
    glw[t * 4 + 0] = (i1 == 0) ? ga : ((i2 == 0) ? gb : 0.0f);
    glw[t * 4 + 1] = (i1 == 1) ? ga : ((i2 == 1) ? gb : 0.0f);
    glw[t * 4 + 2] = (i1 == 2) ? ga : ((i2 == 2) ? gb : 0.0f);
    glw[t * 4 + 3] = (i1 == 3) ? ga : ((i2 == 3) ? gb : 0.0f);
  }
  __syncthreads();   // X + gates settled; partials region free for hid buf0

  const float* gl = (const float*)(S + OFF_GATE);
  const uint16_t* w1t = w1b + (size_t)(wv * 48 + lq) * CC   + 8 * lg;
  const uint16_t* w2t = w2b + (size_t)(wv * 48 + lq) * HIDD + 8 * lg;
  const uint32_t xsw = ((uint32_t)(lq & 7)) << 4;
  uint32_t rowb[4];
  #pragma unroll
  for (int np = 0; np < 4; ++np) rowb[np] = (uint32_t)(16 * np + lq) * 384u;

  f32x4 oacc[3][4];
  #pragma unroll
  for (int m = 0; m < 3; ++m)
    #pragma unroll
    for (int np = 0; np < 4; ++np)
      oacc[m][np] = (f32x4){0.f, 0.f, 0.f, 0.f};

  // ---- Prologue: GEMM1(0) -> gelu(0) -> h0 -> barrier
  {
    f32x4 hacc[3][4];
    #pragma unroll
    for (int m = 0; m < 3; ++m){
      const f32x4 bv = *(const f32x4*)(b1 + wv * 48 + 16 * m + 4 * lg);
      #pragma unroll
      for (int np = 0; np < 4; ++np) hacc[m][np] = bv;
    }
    if (LOADS) g1_phase(w1t, S, rowb, xsw, lg, hacc);
    else       g1_phase_nl(S, rowb, xsw, lg, hacc);
    float gt[4];
    #pragma unroll
    for (int np = 0; np < 4; ++np) gt[np] = gl[(16 * np + lq) * 4 + 0];
    gelu_store(S, OFF_H0, rowb, xsw, wv, lg, gt, hacc);
  }
  __syncthreads();   // h(0) visible

  // ---- Main loop i=0..6: G2_i(hb_r) ; G1_{i+1} ; gelu_{i+1}->hb_w ; barrier
  #pragma unroll 1
  for (int i = 0; i < 7; ++i){
    const uint32_t hb_r = (i & 1) ? OFF_H1 : OFF_H0;
    const uint32_t hb_w = (i & 1) ? OFF_H0 : OFF_H1;
    const int e2 = i >> 1,       ch2 = i & 1;
    const int e1 = (i + 1) >> 1, ch1 = (i + 1) & 1;
    const uint16_t* w2p = w2t + (size_t)(e2 * CC) * HIDD + ch2 * 192;
    const uint16_t* w1p = w1t + (size_t)(e1 * HIDD + ch1 * 192) * CC;

    if (LOADS) g2_phase(w2p, S, hb_r, rowb, xsw, lg, oacc);
    else       g2_phase_nl(S, hb_r, rowb, xsw, lg, oacc);

    f32x4 hacc[3][4];
    #pragma unroll
    for (int m = 0; m < 3; ++m){
      const f32x4 bv = *(const f32x4*)(b1 + e1 * HIDD + ch1 * 192 + wv * 48 + 16 * m + 4 * lg);
      #pragma unroll
      for (int np = 0; np < 4; ++np) hacc[m][np] = bv;
    }
    if (LOADS) g1_phase(w1p, S, rowb, xsw, lg, hacc);
    else       g1_phase_nl(S, rowb, xsw, lg, hacc);

    float gt[4];
    #pragma unroll
    for (int np = 0; np < 4; ++np) gt[np] = gl[(16 * np + lq) * 4 + e1];
    gelu_store(S, hb_w, rowb, xsw, wv, lg, gt, hacc);  // writes OTHER buffer
    __syncthreads();   // hid_{i+1} visible; fences next iter's buffer swap
  }

  // ---- Tail: GEMM2(7) reads h(7) = buf1
  {
    const uint16_t* w2p = w2t + (size_t)(3 * CC) * HIDD + 192;
    if (LOADS) g2_phase(w2p, S, OFF_H1, rowb, xsw, lg, oacc);
    else       g2_phase_nl(S, OFF_H1, rowb, xsw, lg, oacc);
  }

  // ---- Epilogue: gates -> regs, oacc -> LDS transpose [c][65], coalesced store
  const f32x4 g4 = *(const f32x4*)(S + OFF_GATE + lane * 16);
  __syncthreads();   // all hid reads done; outl overlays X + h0
  {
    float* outl = (float*)S;
    #pragma unroll
    for (int m = 0; m < 3; ++m)
      #pragma unroll
      for (int np = 0; np < 4; ++np){
        const int t  = 16 * np + lq;
        const int c0 = wv * 48 + 16 * m + 4 * lg;
        #pragma unroll
        for (int r = 0; r < 4; ++r)
          outl[(c0 + r) * 65 + t] = oacc[m][np][r];
      }
  }
  __syncthreads();
  {
    const int t = lane;
    const float sc = scp[0];
    const float* outl = (const float*)S;
    const float* xbt = xb + n0 + t;
    float* ob = out + (size_t)b * CC * NN + n0 + t;
    #pragma unroll 4
    for (int j = 0; j < 48; ++j){
      const int c = wv * 48 + j;
      const float o  = outl[c * 65 + t];
      const float bt = __builtin_fmaf(g4[0], b2[c],
                        __builtin_fmaf(g4[1], b2[CC + c],
                         __builtin_fmaf(g4[2], b2[2 * CC + c], g4[3] * b2[3 * CC + c])));
      const float xv = xbt[(size_t)c * NN];
      ob[(size_t)c * NN] = __builtin_fmaf(sc, o + bt, xv);
    }
  }
}

// Real kernel (runs LAST, produces d_out)
__global__ __launch_bounds__(256)
__attribute__((amdgpu_waves_per_eu(2, 2)))
void kmoe(const float* __restrict__ x, const float* __restrict__ rw,
          const float* __restrict__ rb, const uint16_t* __restrict__ w1b,
          const float* __restrict__ b1, const uint16_t* __restrict__ w2b,
          const float* __restrict__ b2, const float* __restrict__ scp,
          float* __restrict__ out){
  __shared__ __align__(16) unsigned char S[LDS_SZ];
  moe_body<1>(x, rw, rb, w1b, b1, w2b, b2, scp, out, S);
}

// Ablation kernel: identical minus weight loads. Writes garbage to d_out;
// kmoe overwrites afterwards (deterministic).
__global__ __launch_bounds__(256)
__attribute__((amdgpu_waves_per_eu(2, 2)))
void kab(const float* __restrict__ x, const float* __restrict__ rw,
         const float* __restrict__ rb, const uint16_t* __restrict__ w1b,
         const float* __restrict__ b1, const uint16_t* __restrict__ w2b,
         const float* __restrict__ b2, const float* __restrict__ scp,
         float* __restrict__ out){
  __shared__ __align__(16) unsigned char S[LDS_SZ];
  moe_body<0>(x, rw, rb, w1b, b1, w2b, b2, scp, out, S);
}

extern "C" void kernel_launch(void* const* d_in, const int* in_sizes, int n_in,
                              void* d_out, int out_size, void* d_ws, size_t ws_size,
                              hipStream_t stream){
  const float* x  = (const float*)d_in[0];
  const float* rw = (const float*)d_in[1];
  const float* rb = (const float*)d_in[2];
  const float* w1 = (const float*)d_in[3];
  const float* b1 = (const float*)d_in[4];
  const float* w2 = (const float*)d_in[5];
  const float* b2 = (const float*)d_in[6];
  const float* sc = (const float*)d_in[7];
  float* out = (float*)d_out;
  uint16_t* w1b = (uint16_t*)d_ws;
  uint16_t* w2b = w1b + 294912;

  hipLaunchKernelGGL(kconv, dim3(1152), dim3(256), 0, stream, w1, w2, w1b, w2b);
  // diagnostic ablation first (output overwritten by kmoe below)
  hipLaunchKernelGGL(kab,  dim3(2048), dim3(256), 0, stream,
                     x, rw, rb, w1b, b1, w2b, b2, sc, out);
  // real kernel last: produces the validated output
  hipLaunchKernelGGL(kmoe, dim3(2048), dim3(256), 0, stream,
                     x, rw, rb, w1b, b1, w2b, b2, sc, out);
}

// Round 13
// 178.168 us; speedup vs baseline: 2.9289x; 2.9289x over previous
//
#include <hip/hip_runtime.h>
#include <stdint.h>

typedef __attribute__((ext_vector_type(4))) float f32x4;
typedef unsigned long long u64;
typedef __attribute__((ext_vector_type(2))) u64 u64x2;

#define CC   192
#define NN   16384
#define EE   4
#define HIDD 384

// LDS map (static, 37888 B):
//  [0,     12288)  X tile [64 tok][192 ch] fp8, XOR-swizzled (8B granule) — resident
//  [12288, 24576)  hid buf0 fp8 (router partials f32[16][64] pre-loop only)
//  [24576, 36864)  hid buf1 fp8
//  [36864, 37888)  gates [64 tok][4 e] f32
// Round 13: all-fp8 (w1,w2,X,hid) + asm-held weight prefetch pipeline with
// counted vmcnt and raw s_barrier (no vmcnt drain at barriers). R12's ablation:
// no-load floor 140us, weight delivery +238us. fp8 halves weight bytes; the
// pipeline overlaps delivery with MFMA. Biases ride the asm pipeline so the
// loop has ZERO compiler-visible VMEM (its waits would drain our prefetch).
#define OFF_H0   12288u
#define OFF_H1   24576u
#define OFF_PART 12288
#define OFF_GATE 36864
#define LDS_SZ   37888

// ---- fp8 e4m3fn convert
__device__ __forceinline__ uint32_t fp8b(float f){
  uint32_t u = __builtin_bit_cast(uint32_t, f);
  uint32_t s = (u >> 24) & 0x80u;
  float af = fminf(__builtin_fabsf(f), 448.0f);
  if (af < 0.015625f) return s;                 // FTZ below normal range
  uint32_t v = __builtin_bit_cast(uint32_t, af);
  v += 0x7FFFFu + ((v >> 20) & 1u);             // RNE into 3-bit mantissa
  uint32_t e = (v >> 23) - 120u;                // bias 127 -> 7
  return s | (e << 3) | ((v >> 20) & 7u);
}
#if __has_builtin(__builtin_amdgcn_cvt_pk_fp8_f32)
__device__ __forceinline__ uint32_t fp8x4(float a, float b, float c, float d){
  int v = __builtin_amdgcn_cvt_pk_fp8_f32(a, b, 0, false);
  v = __builtin_amdgcn_cvt_pk_fp8_f32(c, d, v, true);
  return (uint32_t)v;
}
#else
__device__ __forceinline__ uint32_t fp8x4(float a, float b, float c, float d){
  return fp8b(a) | (fp8b(b) << 8) | (fp8b(c) << 16) | (fp8b(d) << 24);
}
#endif
// tanh-form GELU, |err| <= ~3e-3
__device__ __forceinline__ float gelu_f(float v){
  float x2 = v * v;
  float z = v * __builtin_fmaf(x2, -0.1029432f, -2.3022082f);
  float e = __builtin_amdgcn_exp2f(z);
  return v * __builtin_amdgcn_rcpf(1.0f + e);
}
// fp8 MFMA via asm (R8 hardware-proven path + layout)
__device__ __forceinline__ f32x4 mfma8(u64 a, u64 b, f32x4 c){
  asm("v_mfma_f32_16x16x32_fp8_fp8 %0, %1, %2, %0" : "+v"(c) : "v"(a), "v"(b));
  return c;
}

#define WAITV(n) do{ asm volatile("s_waitcnt vmcnt(" #n ")"); \
                     __builtin_amdgcn_sched_barrier(0); }while(0)
#define BARRIER() do{ __builtin_amdgcn_sched_barrier(0); \
                      asm volatile("s_waitcnt lgkmcnt(0)"); \
                      __builtin_amdgcn_s_barrier(); \
                      __builtin_amdgcn_sched_barrier(0); }while(0)

// issue-only: 9 weight dwordx4 (3 bases x offsets 0/16/32) + 3 bias f32x4
__device__ __forceinline__ void issue_w1(const uint8_t* a0, const uint8_t* a1,
                                         const uint8_t* a2, const float* bb,
                                         u64x2 (&w)[9], f32x4 (&bv)[3]){
  asm volatile(
    "global_load_dwordx4 %0, %[A0], off\n\t"
    "global_load_dwordx4 %1, %[A0], off offset:16\n\t"
    "global_load_dwordx4 %2, %[A0], off offset:32\n\t"
    "global_load_dwordx4 %3, %[A1], off\n\t"
    "global_load_dwordx4 %4, %[A1], off offset:16\n\t"
    "global_load_dwordx4 %5, %[A1], off offset:32\n\t"
    "global_load_dwordx4 %6, %[A2], off\n\t"
    "global_load_dwordx4 %7, %[A2], off offset:16\n\t"
    "global_load_dwordx4 %8, %[A2], off offset:32\n\t"
    "global_load_dwordx4 %9, %[B], off\n\t"
    "global_load_dwordx4 %10, %[B], off offset:64\n\t"
    "global_load_dwordx4 %11, %[B], off offset:128"
    : "=&v"(w[0]), "=&v"(w[1]), "=&v"(w[2]), "=&v"(w[3]), "=&v"(w[4]), "=&v"(w[5]),
      "=&v"(w[6]), "=&v"(w[7]), "=&v"(w[8]), "=&v"(bv[0]), "=&v"(bv[1]), "=&v"(bv[2])
    : [A0]"v"(a0), [A1]"v"(a1), [A2]"v"(a2), [B]"v"(bb));
}
__device__ __forceinline__ void issue_w2(const uint8_t* a0, const uint8_t* a1,
                                         const uint8_t* a2, u64x2 (&w)[9]){
  asm volatile(
    "global_load_dwordx4 %0, %[A0], off\n\t"
    "global_load_dwordx4 %1, %[A0], off offset:16\n\t"
    "global_load_dwordx4 %2, %[A0], off offset:32\n\t"
    "global_load_dwordx4 %3, %[A1], off\n\t"
    "global_load_dwordx4 %4, %[A1], off offset:16\n\t"
    "global_load_dwordx4 %5, %[A1], off offset:32\n\t"
    "global_load_dwordx4 %6, %[A2], off\n\t"
    "global_load_dwordx4 %7, %[A2], off offset:16\n\t"
    "global_load_dwordx4 %8, %[A2], off offset:32"
    : "=&v"(w[0]), "=&v"(w[1]), "=&v"(w[2]), "=&v"(w[3]), "=&v"(w[4]), "=&v"(w[5]),
      "=&v"(w[6]), "=&v"(w[7]), "=&v"(w[8])
    : [A0]"v"(a0), [A1]"v"(a1), [A2]"v"(a2));
}

// weight convert + permute: row-local layout [lg][kk][8B] so one dwordx4 at
// lg*(L/4) + j*16 delivers the frags for kk=2j, 2j+1 (frag k = kk*32+lg*8+b).
extern "C" __global__ void kconv(const float* __restrict__ w1, const float* __restrict__ w2,
                                 uint8_t* __restrict__ w1f8, uint8_t* __restrict__ w2f8){
  int i = blockIdx.x * 256 + threadIdx.x;
  {
    int row = i / 192, k = i % 192;
    int o = k >> 3, kk = o >> 2, lg = o & 3, bi = k & 7;
    w1f8[(size_t)row * 192 + lg * 48 + kk * 8 + bi] = (uint8_t)fp8b(w1[i]);
  }
  {
    int row = i / 384, k = i % 384;
    int o = k >> 3, kk = o >> 2, lg = o & 3, bi = k & 7;
    w2f8[(size_t)row * 384 + lg * 96 + kk * 8 + bi] = (uint8_t)fp8b(w2[i]);
  }
}

__global__ __launch_bounds__(256)
__attribute__((amdgpu_waves_per_eu(2, 2)))
void kmoe(const float* __restrict__ x, const float* __restrict__ rw,
          const float* __restrict__ rb, const uint8_t* __restrict__ w1f8,
          const float* __restrict__ b1, const uint8_t* __restrict__ w2f8,
          const float* __restrict__ b2, const float* __restrict__ scp,
          float* __restrict__ out)
{
  __shared__ __align__(16) unsigned char S[LDS_SZ];
  const int tid  = threadIdx.x;
  const int lane = tid & 63;
  const int wv   = tid >> 6;
  const int lq   = lane & 15;
  const int lg   = lane >> 4;
  const int tile = blockIdx.x;
  const int b    = tile >> 8;
  const int n0   = (tile & 255) << 6;
  const float* xb = x + (size_t)b * CC * NN;

  // ---- stage X (fp8, swizzled, 8B writes) + fp32 router partials
  {
    const int t = lane;
    const uint32_t rowbase = (uint32_t)t * 192u;
    const uint32_t sw = ((uint32_t)(t & 7)) << 3;
    float a0 = 0.f, a1 = 0.f, a2 = 0.f, a3 = 0.f;
    #pragma unroll
    for (int jj = 0; jj < 6; ++jj){
      float v[8];
      #pragma unroll
      for (int j = 0; j < 8; ++j){
        const int c = wv * 48 + jj * 8 + j;
        v[j] = xb[(size_t)c * NN + n0 + t];
        a0 = __builtin_fmaf(v[j], rw[c],          a0);
        a1 = __builtin_fmaf(v[j], rw[CC + c],     a1);
        a2 = __builtin_fmaf(v[j], rw[2 * CC + c], a2);
        a3 = __builtin_fmaf(v[j], rw[3 * CC + c], a3);
      }
      uint2 p;
      p.x = fp8x4(v[0], v[1], v[2], v[3]);
      p.y = fp8x4(v[4], v[5], v[6], v[7]);
      *(uint2*)(S + rowbase + (((uint32_t)(wv * 48 + jj * 8)) ^ sw)) = p;
    }
    float* pl = (float*)(S + OFF_PART);
    pl[(wv * 4 + 0) * 64 + t] = a0;
    pl[(wv * 4 + 1) * 64 + t] = a1;
    pl[(wv * 4 + 2) * 64 + t] = a2;
    pl[(wv * 4 + 3) * 64 + t] = a3;
  }
  __syncthreads();

  // ---- router finalize (fp32, top-2 tie->lower, softmax) -> gates
  if (tid < 64){
    const int t = tid;
    const float* pl = (const float*)(S + OFF_PART);
    float l0 = rb[0], l1 = rb[1], l2 = rb[2], l3 = rb[3];
    #pragma unroll
    for (int cg = 0; cg < 4; ++cg){
      l0 += pl[(cg * 4 + 0) * 64 + t];
      l1 += pl[(cg * 4 + 1) * 64 + t];
      l2 += pl[(cg * 4 + 2) * 64 + t];
      l3 += pl[(cg * 4 + 3) * 64 + t];
    }
    int i1 = 0; float v1 = l0;
    if (l1 > v1){ v1 = l1; i1 = 1; }
    if (l2 > v1){ v1 = l2; i1 = 2; }
    if (l3 > v1){ v1 = l3; i1 = 3; }
    float v2 = -3.0e38f; int i2 = 0;
    if (i1 != 0){ v2 = l0; i2 = 0; }
    if (i1 != 1 && l1 > v2){ v2 = l1; i2 = 1; }
    if (i1 != 2 && l2 > v2){ v2 = l2; i2 = 2; }
    if (i1 != 3 && l3 > v2){ v2 = l3; i2 = 3; }
    const float ex = __expf(v2 - v1);
    const float ga = 1.0f / (1.0f + ex);
    const float gb = ex * ga;
    float* glw = (float*)(S + OFF_GATE);
    glw[t * 4 + 0] = (i1 == 0) ? ga : ((i2 == 0) ? gb : 0.0f);
    glw[t * 4 + 1] = (i1 == 1) ? ga : ((i2 == 1) ? gb : 0.0f);
    glw[t * 4 + 2] = (i1 == 2) ? ga : ((i2 == 2) ? gb : 0.0f);
    glw[t * 4 + 3] = (i1 == 3) ? ga : ((i2 == 3) ? gb : 0.0f);
  }
  __syncthreads();   // full drain OK here: nothing prefetched yet

  const float* gl = (const float*)(S + OFF_GATE);
  const uint32_t xsw = ((uint32_t)(lq & 7)) << 3;
  uint32_t rowb[4];
  #pragma unroll
  for (int np = 0; np < 4; ++np) rowb[np] = (uint32_t)(16 * np + lq) * 192u;

  // per-lane weight/bias bases (phase p: e=p>>1, ch=p&1)
  const uint8_t* w1l = w1f8 + (size_t)(wv * 48 + lq) * 192 + lg * 48;  // + p*36864
  const uint8_t* w2l = w2f8 + (size_t)(wv * 48 + lq) * 384 + lg * 96;  // + e*73728 + ch*48
  const float*   b1l = b1 + wv * 48 + 4 * lg;                          // + p*192 (+16m)

  u64x2 W1[9], W2[9];
  f32x4 BV[3];
  f32x4 oacc[3][4];
  #pragma unroll
  for (int m = 0; m < 3; ++m)
    #pragma unroll
    for (int np = 0; np < 4; ++np)
      oacc[m][np] = (f32x4){0.f, 0.f, 0.f, 0.f};

#define ISSUE_W1(p) issue_w1(w1l + (size_t)(p) * 36864, \
                             w1l + (size_t)(p) * 36864 + 16 * 192, \
                             w1l + (size_t)(p) * 36864 + 32 * 192, \
                             b1l + (p) * 192, W1, BV)
#define ISSUE_W2(e, ch) issue_w2(w2l + (size_t)(e) * 73728 + (ch) * 48, \
                                 w2l + (size_t)(e) * 73728 + (ch) * 48 + 16 * 384, \
                                 w2l + (size_t)(e) * 73728 + (ch) * 48 + 32 * 384, W2)

  // GEMM1 compute: A = w1 frags (regs), B = X (LDS fp8), bias-init
#define G1_COMP(hacc) do{ \
    _Pragma("unroll") \
    for (int m = 0; m < 3; ++m) \
      _Pragma("unroll") \
      for (int np = 0; np < 4; ++np) hacc[m][np] = BV[m]; \
    __builtin_amdgcn_s_setprio(1); \
    _Pragma("unroll") \
    for (int kk = 0; kk < 6; ++kk){ \
      u64 xk[4]; \
      _Pragma("unroll") \
      for (int np = 0; np < 4; ++np) \
        xk[np] = *(const u64*)(S + rowb[np] + (((uint32_t)(kk * 32 + lg * 8)) ^ xsw)); \
      _Pragma("unroll") \
      for (int np = 0; np < 4; ++np) \
        _Pragma("unroll") \
        for (int m = 0; m < 3; ++m){ \
          const u64 a = (kk & 1) ? W1[m * 3 + (kk >> 1)].y : W1[m * 3 + (kk >> 1)].x; \
          hacc[m][np] = mfma8(a, xk[np], hacc[m][np]); \
        } \
    } \
    __builtin_amdgcn_s_setprio(0); }while(0)

#define G2_COMP(hb) do{ \
    __builtin_amdgcn_s_setprio(1); \
    _Pragma("unroll") \
    for (int kk = 0; kk < 6; ++kk){ \
      u64 hf[4]; \
      _Pragma("unroll") \
      for (int np = 0; np < 4; ++np) \
        hf[np] = *(const u64*)(S + (hb) + rowb[np] + (((uint32_t)(kk * 32 + lg * 8)) ^ xsw)); \
      _Pragma("unroll") \
      for (int np = 0; np < 4; ++np) \
        _Pragma("unroll") \
        for (int m = 0; m < 3; ++m){ \
          const u64 a = (kk & 1) ? W2[m * 3 + (kk >> 1)].y : W2[m * 3 + (kk >> 1)].x; \
          oacc[m][np] = mfma8(a, hf[np], oacc[m][np]); \
        } \
    } \
    __builtin_amdgcn_s_setprio(0); }while(0)

#define GELU_ST(hb, e, hacc) do{ \
    _Pragma("unroll") \
    for (int np = 0; np < 4; ++np){ \
      const float g = gl[(16 * np + lq) * 4 + (e)]; \
      _Pragma("unroll") \
      for (int m = 0; m < 3; ++m){ \
        const uint32_t colb = (uint32_t)(48 * wv + 16 * m + 4 * lg); \
        *(uint32_t*)(S + (hb) + rowb[np] + (colb ^ xsw)) = \
          fp8x4(gelu_f(hacc[m][np][0]) * g, gelu_f(hacc[m][np][1]) * g, \
                gelu_f(hacc[m][np][2]) * g, gelu_f(hacc[m][np][3]) * g); \
      } \
    } }while(0)

  // ---- prologue: phase 0 G1 -> gelu -> H0 (pipeline fill: 21 loads in flight)
  {
    ISSUE_W1(0);
    ISSUE_W2(0, 0);
    WAITV(9);                 // W1(0)+bias done; W2(0):9 outstanding
    f32x4 hacc[3][4];
    G1_COMP(hacc);
    GELU_ST(OFF_H0, 0, hacc);
    ISSUE_W1(1);              // outstanding: W2(0):9 + W1(1):12 = 21
  }
  BARRIER();

  // ---- main loop i=0..6: G2(i) ; G1(i+1) ; gelu -> other buf ; raw barrier
  #pragma unroll 1
  for (int i = 0; i < 7; ++i){
    const uint32_t hb_r = (i & 1) ? OFF_H1 : OFF_H0;
    const uint32_t hb_w = (i & 1) ? OFF_H0 : OFF_H1;
    WAITV(12);                // W2(i) done; W1(i+1):12 outstanding
    G2_COMP(hb_r);
    {
      const int p = i + 1;
      ISSUE_W2(p >> 1, p & 1);   // 12+9 = 21
    }
    WAITV(9);                 // W1(i+1)+bias done; W2(i+1):9 outstanding
    f32x4 hacc[3][4];
    G1_COMP(hacc);
    GELU_ST(hb_w, (i + 1) >> 1, hacc);
    if (i < 6) ISSUE_W1(i + 2);   // 9+12 = 21
    BARRIER();
  }

  // ---- tail: G2(7) reads H1
  WAITV(0);
  G2_COMP(OFF_H1);

  // ---- epilogue: direct stores (64B segments, L2 write-combines to lines)
  {
    const float sc = scp[0];
    f32x4 g4v[4];
    #pragma unroll
    for (int np = 0; np < 4; ++np)
      g4v[np] = *(const f32x4*)(S + OFF_GATE + (16 * np + lq) * 16);
    const size_t obase = (size_t)b * CC * NN + n0;
    #pragma unroll
    for (int m = 0; m < 3; ++m){
      const int f0 = 48 * wv + 16 * m + 4 * lg;
      f32x4 b2q[4];
      #pragma unroll
      for (int e = 0; e < 4; ++e)
        b2q[e] = *(const f32x4*)(b2 + e * CC + f0);
      #pragma unroll
      for (int np = 0; np < 4; ++np){
        const int tok = 16 * np + lq;
        #pragma unroll
        for (int r = 0; r < 4; ++r){
          const float bt = __builtin_fmaf(g4v[np][0], b2q[0][r],
                            __builtin_fmaf(g4v[np][1], b2q[1][r],
                             __builtin_fmaf(g4v[np][2], b2q[2][r],
                                            g4v[np][3] * b2q[3][r])));
          const size_t off = obase + (size_t)(f0 + r) * NN + tok;
          out[off] = __builtin_fmaf(sc, oacc[m][np][r] + bt, x[off]);
        }
      }
    }
  }
#undef ISSUE_W1
#undef ISSUE_W2
#undef G1_COMP
#undef G2_COMP
#undef GELU_ST
}

extern "C" void kernel_launch(void* const* d_in, const int* in_sizes, int n_in,
                              void* d_out, int out_size, void* d_ws, size_t ws_size,
                              hipStream_t stream){
  const float* x  = (const float*)d_in[0];
  const float* rw = (const float*)d_in[1];
  const float* rb = (const float*)d_in[2];
  const float* w1 = (const float*)d_in[3];
  const float* b1 = (const float*)d_in[4];
  const float* w2 = (const float*)d_in[5];
  const float* b2 = (const float*)d_in[6];
  const float* sc = (const float*)d_in[7];
  float* out = (float*)d_out;
  uint8_t* w1f8 = (uint8_t*)d_ws;
  uint8_t* w2f8 = w1f8 + 294912;

  hipLaunchKernelGGL(kconv, dim3(1152), dim3(256), 0, stream, w1, w2, w1f8, w2f8);
  hipLaunchKernelGGL(kmoe,  dim3(2048), dim3(256), 0, stream,
                     x, rw, rb, w1f8, b1, w2f8, b2, sc, out);
}

// Round 14
// 165.929 us; speedup vs baseline: 3.1450x; 1.0738x over previous
//
#include <hip/hip_runtime.h>
#include <stdint.h>

typedef __attribute__((ext_vector_type(4))) float f32x4;
typedef unsigned long long u64;
typedef __attribute__((ext_vector_type(2))) u64 u64x2;

#define CC   192
#define NN   16384
#define EE   4
#define HIDD 384

// LDS map (static, 39424 B), rows padded to 200 B (50 words; 50%32=18,
// gcd(18,32)=2 -> 18*lq covers all 16 even banks once for lq=0..15):
//  [0,     12800)  X tile [64 tok][200B] fp8 — resident whole kernel
//  [12800, 25600)  hid buf0 [64][200B] fp8 (router partials f32[16][64] pre-loop)
//  [25600, 38400)  hid buf1
//  [38400, 39424)  gates [64 tok][4 e] f32
// Round 14 vs R13 (pipeline frozen): (1) stride-200 rows + NO xor swizzle —
// R13's bf16-era 8B-granule xor was wrong for fp8 geometry (conflicts 3x'd to
// 14.5M); stride-200 makes b64 reads 4-way-uniform (= HW minimum) and 4B
// writes 2-way (free). (2) sigmoid GELU x*sigma(1.702x): -4 VALU cyc/value.
#define OFF_H0   12800u
#define OFF_H1   25600u
#define OFF_PART 12800
#define OFF_GATE 38400
#define LDS_SZ   39424
#define ROWS     200u

// ---- fp8 e4m3fn convert
__device__ __forceinline__ uint32_t fp8b(float f){
  uint32_t u = __builtin_bit_cast(uint32_t, f);
  uint32_t s = (u >> 24) & 0x80u;
  float af = fminf(__builtin_fabsf(f), 448.0f);
  if (af < 0.015625f) return s;                 // FTZ below normal range
  uint32_t v = __builtin_bit_cast(uint32_t, af);
  v += 0x7FFFFu + ((v >> 20) & 1u);             // RNE into 3-bit mantissa
  uint32_t e = (v >> 23) - 120u;                // bias 127 -> 7
  return s | (e << 3) | ((v >> 20) & 7u);
}
#if __has_builtin(__builtin_amdgcn_cvt_pk_fp8_f32)
__device__ __forceinline__ uint32_t fp8x4(float a, float b, float c, float d){
  int v = __builtin_amdgcn_cvt_pk_fp8_f32(a, b, 0, false);
  v = __builtin_amdgcn_cvt_pk_fp8_f32(c, d, v, true);
  return (uint32_t)v;
}
#else
__device__ __forceinline__ uint32_t fp8x4(float a, float b, float c, float d){
  return fp8b(a) | (fp8b(b) << 8) | (fp8b(c) << 16) | (fp8b(d) << 24);
}
#endif
// sigmoid-form GELU: x*sigma(1.702x). |err| <= ~0.02 pre-gate; budget OK.
__device__ __forceinline__ float gelu_f(float v){
  float e = __builtin_amdgcn_exp2f(v * -2.4554669f);   // exp2(-1.702*log2e*x)
  return v * __builtin_amdgcn_rcpf(1.0f + e);
}
// fp8 MFMA via asm (R8 hardware-proven path + layout)
__device__ __forceinline__ f32x4 mfma8(u64 a, u64 b, f32x4 c){
  asm("v_mfma_f32_16x16x32_fp8_fp8 %0, %1, %2, %0" : "+v"(c) : "v"(a), "v"(b));
  return c;
}

#define WAITV(n) do{ asm volatile("s_waitcnt vmcnt(" #n ")"); \
                     __builtin_amdgcn_sched_barrier(0); }while(0)
#define BARRIER() do{ __builtin_amdgcn_sched_barrier(0); \
                      asm volatile("s_waitcnt lgkmcnt(0)"); \
                      __builtin_amdgcn_s_barrier(); \
                      __builtin_amdgcn_sched_barrier(0); }while(0)

// issue-only: 9 weight dwordx4 (3 bases x offsets 0/16/32) + 3 bias f32x4
__device__ __forceinline__ void issue_w1(const uint8_t* a0, const uint8_t* a1,
                                         const uint8_t* a2, const float* bb,
                                         u64x2 (&w)[9], f32x4 (&bv)[3]){
  asm volatile(
    "global_load_dwordx4 %0, %[A0], off\n\t"
    "global_load_dwordx4 %1, %[A0], off offset:16\n\t"
    "global_load_dwordx4 %2, %[A0], off offset:32\n\t"
    "global_load_dwordx4 %3, %[A1], off\n\t"
    "global_load_dwordx4 %4, %[A1], off offset:16\n\t"
    "global_load_dwordx4 %5, %[A1], off offset:32\n\t"
    "global_load_dwordx4 %6, %[A2], off\n\t"
    "global_load_dwordx4 %7, %[A2], off offset:16\n\t"
    "global_load_dwordx4 %8, %[A2], off offset:32\n\t"
    "global_load_dwordx4 %9, %[B], off\n\t"
    "global_load_dwordx4 %10, %[B], off offset:64\n\t"
    "global_load_dwordx4 %11, %[B], off offset:128"
    : "=&v"(w[0]), "=&v"(w[1]), "=&v"(w[2]), "=&v"(w[3]), "=&v"(w[4]), "=&v"(w[5]),
      "=&v"(w[6]), "=&v"(w[7]), "=&v"(w[8]), "=&v"(bv[0]), "=&v"(bv[1]), "=&v"(bv[2])
    : [A0]"v"(a0), [A1]"v"(a1), [A2]"v"(a2), [B]"v"(bb));
}
__device__ __forceinline__ void issue_w2(const uint8_t* a0, const uint8_t* a1,
                                         const uint8_t* a2, u64x2 (&w)[9]){
  asm volatile(
    "global_load_dwordx4 %0, %[A0], off\n\t"
    "global_load_dwordx4 %1, %[A0], off offset:16\n\t"
    "global_load_dwordx4 %2, %[A0], off offset:32\n\t"
    "global_load_dwordx4 %3, %[A1], off\n\t"
    "global_load_dwordx4 %4, %[A1], off offset:16\n\t"
    "global_load_dwordx4 %5, %[A1], off offset:32\n\t"
    "global_load_dwordx4 %6, %[A2], off\n\t"
    "global_load_dwordx4 %7, %[A2], off offset:16\n\t"
    "global_load_dwordx4 %8, %[A2], off offset:32"
    : "=&v"(w[0]), "=&v"(w[1]), "=&v"(w[2]), "=&v"(w[3]), "=&v"(w[4]), "=&v"(w[5]),
      "=&v"(w[6]), "=&v"(w[7]), "=&v"(w[8])
    : [A0]"v"(a0), [A1]"v"(a1), [A2]"v"(a2));
}

// weight convert + permute: row-local layout [lg][kk][8B] so one dwordx4 at
// lg*(L/4) + j*16 delivers the frags for kk=2j, 2j+1 (frag k = kk*32+lg*8+b).
extern "C" __global__ void kconv(const float* __restrict__ w1, const float* __restrict__ w2,
                                 uint8_t* __restrict__ w1f8, uint8_t* __restrict__ w2f8){
  int i = blockIdx.x * 256 + threadIdx.x;
  {
    int row = i / 192, k = i % 192;
    int o = k >> 3, kk = o >> 2, lg = o & 3, bi = k & 7;
    w1f8[(size_t)row * 192 + lg * 48 + kk * 8 + bi] = (uint8_t)fp8b(w1[i]);
  }
  {
    int row = i / 384, k = i % 384;
    int o = k >> 3, kk = o >> 2, lg = o & 3, bi = k & 7;
    w2f8[(size_t)row * 384 + lg * 96 + kk * 8 + bi] = (uint8_t)fp8b(w2[i]);
  }
}

__global__ __launch_bounds__(256)
__attribute__((amdgpu_waves_per_eu(2, 2)))
void kmoe(const float* __restrict__ x, const float* __restrict__ rw,
          const float* __restrict__ rb, const uint8_t* __restrict__ w1f8,
          const float* __restrict__ b1, const uint8_t* __restrict__ w2f8,
          const float* __restrict__ b2, const float* __restrict__ scp,
          float* __restrict__ out)
{
  __shared__ __align__(16) unsigned char S[LDS_SZ];
  const int tid  = threadIdx.x;
  const int lane = tid & 63;
  const int wv   = tid >> 6;
  const int lq   = lane & 15;
  const int lg   = lane >> 4;
  const int tile = blockIdx.x;
  const int b    = tile >> 8;
  const int n0   = (tile & 255) << 6;
  const float* xb = x + (size_t)b * CC * NN;

  // ---- stage X (fp8, stride-200 rows, 8B writes) + fp32 router partials
  {
    const int t = lane;
    const uint32_t rowbase = (uint32_t)t * ROWS;
    float a0 = 0.f, a1 = 0.f, a2 = 0.f, a3 = 0.f;
    #pragma unroll
    for (int jj = 0; jj < 6; ++jj){
      float v[8];
      #pragma unroll
      for (int j = 0; j < 8; ++j){
        const int c = wv * 48 + jj * 8 + j;
        v[j] = xb[(size_t)c * NN + n0 + t];
        a0 = __builtin_fmaf(v[j], rw[c],          a0);
        a1 = __builtin_fmaf(v[j], rw[CC + c],     a1);
        a2 = __builtin_fmaf(v[j], rw[2 * CC + c], a2);
        a3 = __builtin_fmaf(v[j], rw[3 * CC + c], a3);
      }
      uint2 p;
      p.x = fp8x4(v[0], v[1], v[2], v[3]);
      p.y = fp8x4(v[4], v[5], v[6], v[7]);
      *(uint2*)(S + rowbase + (uint32_t)(wv * 48 + jj * 8)) = p;
    }
    float* pl = (float*)(S + OFF_PART);
    pl[(wv * 4 + 0) * 64 + t] = a0;
    pl[(wv * 4 + 1) * 64 + t] = a1;
    pl[(wv * 4 + 2) * 64 + t] = a2;
    pl[(wv * 4 + 3) * 64 + t] = a3;
  }
  __syncthreads();

  // ---- router finalize (fp32, top-2 tie->lower, softmax) -> gates
  if (tid < 64){
    const int t = tid;
    const float* pl = (const float*)(S + OFF_PART);
    float l0 = rb[0], l1 = rb[1], l2 = rb[2], l3 = rb[3];
    #pragma unroll
    for (int cg = 0; cg < 4; ++cg){
      l0 += pl[(cg * 4 + 0) * 64 + t];
      l1 += pl[(cg * 4 + 1) * 64 + t];
      l2 += pl[(cg * 4 + 2) * 64 + t];
      l3 += pl[(cg * 4 + 3) * 64 + t];
    }
    int i1 = 0; float v1 = l0;
    if (l1 > v1){ v1 = l1; i1 = 1; }
    if (l2 > v1){ v1 = l2; i1 = 2; }
    if (l3 > v1){ v1 = l3; i1 = 3; }
    float v2 = -3.0e38f; int i2 = 0;
    if (i1 != 0){ v2 = l0; i2 = 0; }
    if (i1 != 1 && l1 > v2){ v2 = l1; i2 = 1; }
    if (i1 != 2 && l2 > v2){ v2 = l2; i2 = 2; }
    if (i1 != 3 && l3 > v2){ v2 = l3; i2 = 3; }
    const float ex = __expf(v2 - v1);
    const float ga = 1.0f / (1.0f + ex);
    const float gb = ex * ga;
    float* glw = (float*)(S + OFF_GATE);
    glw[t * 4 + 0] = (i1 == 0) ? ga : ((i2 == 0) ? gb : 0.0f);
    glw[t * 4 + 1] = (i1 == 1) ? ga : ((i2 == 1) ? gb : 0.0f);
    glw[t * 4 + 2] = (i1 == 2) ? ga : ((i2 == 2) ? gb : 0.0f);
    glw[t * 4 + 3] = (i1 == 3) ? ga : ((i2 == 3) ? gb : 0.0f);
  }
  __syncthreads();   // full drain OK here: nothing prefetched yet

  const float* gl = (const float*)(S + OFF_GATE);
  uint32_t rowb[4];
  #pragma unroll
  for (int np = 0; np < 4; ++np) rowb[np] = (uint32_t)(16 * np + lq) * ROWS;

  // per-lane weight/bias bases (phase p: e=p>>1, ch=p&1)
  const uint8_t* w1l = w1f8 + (size_t)(wv * 48 + lq) * 192 + lg * 48;  // + p*36864
  const uint8_t* w2l = w2f8 + (size_t)(wv * 48 + lq) * 384 + lg * 96;  // + e*73728 + ch*48
  const float*   b1l = b1 + wv * 48 + 4 * lg;                          // + p*192 (+16m)

  u64x2 W1[9], W2[9];
  f32x4 BV[3];
  f32x4 oacc[3][4];
  #pragma unroll
  for (int m = 0; m < 3; ++m)
    #pragma unroll
    for (int np = 0; np < 4; ++np)
      oacc[m][np] = (f32x4){0.f, 0.f, 0.f, 0.f};

#define ISSUE_W1(p) issue_w1(w1l + (size_t)(p) * 36864, \
                             w1l + (size_t)(p) * 36864 + 16 * 192, \
                             w1l + (size_t)(p) * 36864 + 32 * 192, \
                             b1l + (p) * 192, W1, BV)
#define ISSUE_W2(e, ch) issue_w2(w2l + (size_t)(e) * 73728 + (ch) * 48, \
                                 w2l + (size_t)(e) * 73728 + (ch) * 48 + 16 * 384, \
                                 w2l + (size_t)(e) * 73728 + (ch) * 48 + 32 * 384, W2)

  // GEMM1 compute: A = w1 frags (regs), B = X (LDS fp8), bias-init
#define G1_COMP(hacc) do{ \
    _Pragma("unroll") \
    for (int m = 0; m < 3; ++m) \
      _Pragma("unroll") \
      for (int np = 0; np < 4; ++np) hacc[m][np] = BV[m]; \
    __builtin_amdgcn_s_setprio(1); \
    _Pragma("unroll") \
    for (int kk = 0; kk < 6; ++kk){ \
      u64 xk[4]; \
      _Pragma("unroll") \
      for (int np = 0; np < 4; ++np) \
        xk[np] = *(const u64*)(S + rowb[np] + (uint32_t)(kk * 32 + lg * 8)); \
      _Pragma("unroll") \
      for (int np = 0; np < 4; ++np) \
        _Pragma("unroll") \
        for (int m = 0; m < 3; ++m){ \
          const u64 a = (kk & 1) ? W1[m * 3 + (kk >> 1)].y : W1[m * 3 + (kk >> 1)].x; \
          hacc[m][np] = mfma8(a, xk[np], hacc[m][np]); \
        } \
    } \
    __builtin_amdgcn_s_setprio(0); }while(0)

#define G2_COMP(hb) do{ \
    __builtin_amdgcn_s_setprio(1); \
    _Pragma("unroll") \
    for (int kk = 0; kk < 6; ++kk){ \
      u64 hf[4]; \
      _Pragma("unroll") \
      for (int np = 0; np < 4; ++np) \
        hf[np] = *(const u64*)(S + (hb) + rowb[np] + (uint32_t)(kk * 32 + lg * 8)); \
      _Pragma("unroll") \
      for (int np = 0; np < 4; ++np) \
        _Pragma("unroll") \
        for (int m = 0; m < 3; ++m){ \
          const u64 a = (kk & 1) ? W2[m * 3 + (kk >> 1)].y : W2[m * 3 + (kk >> 1)].x; \
          oacc[m][np] = mfma8(a, hf[np], oacc[m][np]); \
        } \
    } \
    __builtin_amdgcn_s_setprio(0); }while(0)

#define GELU_ST(hb, e, hacc) do{ \
    _Pragma("unroll") \
    for (int np = 0; np < 4; ++np){ \
      const float g = gl[(16 * np + lq) * 4 + (e)]; \
      _Pragma("unroll") \
      for (int m = 0; m < 3; ++m){ \
        const uint32_t colb = (uint32_t)(48 * wv + 16 * m + 4 * lg); \
        *(uint32_t*)(S + (hb) + rowb[np] + colb) = \
          fp8x4(gelu_f(hacc[m][np][0]) * g, gelu_f(hacc[m][np][1]) * g, \
                gelu_f(hacc[m][np][2]) * g, gelu_f(hacc[m][np][3]) * g); \
      } \
    } }while(0)

  // ---- prologue: phase 0 G1 -> gelu -> H0 (pipeline fill: 21 loads in flight)
  {
    ISSUE_W1(0);
    ISSUE_W2(0, 0);
    WAITV(9);                 // W1(0)+bias done; W2(0):9 outstanding
    f32x4 hacc[3][4];
    G1_COMP(hacc);
    GELU_ST(OFF_H0, 0, hacc);
    ISSUE_W1(1);              // outstanding: W2(0):9 + W1(1):12 = 21
  }
  BARRIER();

  // ---- main loop i=0..6: G2(i) ; G1(i+1) ; gelu -> other buf ; raw barrier
  #pragma unroll 1
  for (int i = 0; i < 7; ++i){
    const uint32_t hb_r = (i & 1) ? OFF_H1 : OFF_H0;
    const uint32_t hb_w = (i & 1) ? OFF_H0 : OFF_H1;
    WAITV(12);                // W2(i) done; W1(i+1):12 outstanding
    G2_COMP(hb_r);
    {
      const int p = i + 1;
      ISSUE_W2(p >> 1, p & 1);   // 12+9 = 21
    }
    WAITV(9);                 // W1(i+1)+bias done; W2(i+1):9 outstanding
    f32x4 hacc[3][4];
    G1_COMP(hacc);
    GELU_ST(hb_w, (i + 1) >> 1, hacc);
    if (i < 6) ISSUE_W1(i + 2);   // 9+12 = 21
    BARRIER();
  }

  // ---- tail: G2(7) reads H1
  WAITV(0);
  G2_COMP(OFF_H1);

  // ---- epilogue: direct stores (64B segments, L2 write-combines to lines)
  {
    const float sc = scp[0];
    f32x4 g4v[4];
    #pragma unroll
    for (int np = 0; np < 4; ++np)
      g4v[np] = *(const f32x4*)(S + OFF_GATE + (16 * np + lq) * 16);
    const size_t obase = (size_t)b * CC * NN + n0;
    #pragma unroll
    for (int m = 0; m < 3; ++m){
      const int f0 = 48 * wv + 16 * m + 4 * lg;
      f32x4 b2q[4];
      #pragma unroll
      for (int e = 0; e < 4; ++e)
        b2q[e] = *(const f32x4*)(b2 + e * CC + f0);
      #pragma unroll
      for (int np = 0; np < 4; ++np){
        const int tok = 16 * np + lq;
        #pragma unroll
        for (int r = 0; r < 4; ++r){
          const float bt = __builtin_fmaf(g4v[np][0], b2q[0][r],
                            __builtin_fmaf(g4v[np][1], b2q[1][r],
                             __builtin_fmaf(g4v[np][2], b2q[2][r],
                                            g4v[np][3] * b2q[3][r])));
          const size_t off = obase + (size_t)(f0 + r) * NN + tok;
          out[off] = __builtin_fmaf(sc, oacc[m][np][r] + bt, x[off]);
        }
      }
    }
  }
#undef ISSUE_W1
#undef ISSUE_W2
#undef G1_COMP
#undef G2_COMP
#undef GELU_ST
}

extern "C" void kernel_launch(void* const* d_in, const int* in_sizes, int n_in,
                              void* d_out, int out_size, void* d_ws, size_t ws_size,
                              hipStream_t stream){
  const float* x  = (const float*)d_in[0];
  const float* rw = (const float*)d_in[1];
  const float* rb = (const float*)d_in[2];
  const float* w1 = (const float*)d_in[3];
  const float* b1 = (const float*)d_in[4];
  const float* w2 = (const float*)d_in[5];
  const float* b2 = (const float*)d_in[6];
  const float* sc = (const float*)d_in[7];
  float* out = (float*)d_out;
  uint8_t* w1f8 = (uint8_t*)d_ws;
  uint8_t* w2f8 = w1f8 + 294912;

  hipLaunchKernelGGL(kconv, dim3(1152), dim3(256), 0, stream, w1, w2, w1f8, w2f8);
  hipLaunchKernelGGL(kmoe,  dim3(2048), dim3(256), 0, stream,
                     x, rw, rb, w1f8, b1, w2f8, b2, sc, out);
}